// Round 1
// baseline (3138.257 us; speedup 1.0000x reference)
//
#include <hip/hip_runtime.h>
#include <hip/hip_bf16.h>
#include <math.h>

#define N_NODES 40000
#define N_EDGES 400000
#define GCLIP 511

__device__ __forceinline__ unsigned short f2bf(float f) {
    __hip_bfloat16 h = __float2bfloat16(f);
    return *(unsigned short*)&h;
}
__device__ __forceinline__ float bf2f(unsigned short u) {
    __hip_bfloat16 h = *(__hip_bfloat16*)&u;
    return __bfloat162float(h);
}

// ---------------- CSR build ----------------
__global__ void count_kernel(const int* __restrict__ dst, int* __restrict__ cnt, int E) {
    int e = blockIdx.x * 256 + threadIdx.x;
    if (e < E) atomicAdd(&cnt[dst[e]], 1);
}

__global__ void scan_kernel(const int* __restrict__ cnt, int* __restrict__ row_ptr,
                            int* __restrict__ cursor, int n) {
    __shared__ int sm[1024];
    int tid = threadIdx.x;
    int running = 0;
    for (int base = 0; base < n; base += 1024) {
        int i = base + tid;
        int v = (i < n) ? cnt[i] : 0;
        sm[tid] = v;
        __syncthreads();
        for (int off = 1; off < 1024; off <<= 1) {
            int t = (tid >= off) ? sm[tid - off] : 0;
            __syncthreads();
            sm[tid] += t;
            __syncthreads();
        }
        int incl = sm[tid];
        if (i < n) { int ex = running + incl - v; row_ptr[i] = ex; cursor[i] = ex; }
        running += sm[1023];
        __syncthreads();
    }
    if (tid == 0) row_ptr[n] = running;
}

__global__ void scatter_kernel(const int* __restrict__ dst, int* __restrict__ cursor,
                               int* __restrict__ csr_eid, int E) {
    int e = blockIdx.x * 256 + threadIdx.x;
    if (e < E) {
        int pos = atomicAdd(&cursor[dst[e]], 1);
        csr_eid[pos] = e;
    }
}

// ---------------- feature build: [x | gp[gid] | sp | ep[gid]] -> [N,16] ----------------
__global__ void feat_kernel(const float* __restrict__ x, const int* __restrict__ batch,
                            const int* __restrict__ gptr, const int* __restrict__ tgid,
                            const float* __restrict__ gp, const float* __restrict__ sp,
                            const float* __restrict__ ep, float* __restrict__ feat, int n) {
    int idx = blockIdx.x * 256 + threadIdx.x;
    if (idx >= n * 16) return;
    int node = idx >> 4, c = idx & 15;
    float v;
    if (c < 4) {
        v = x[node * 4 + c];
    } else if (c < 7) {
        int gid = gptr[batch[node]] + tgid[node];
        gid = min(max(gid, 0), GCLIP);
        v = gp[gid * 3 + (c - 4)];
    } else if (c < 10) {
        v = sp[node * 3 + (c - 7)];
    } else {
        int gid = gptr[batch[node]] + tgid[node];
        gid = min(max(gid, 0), GCLIP);
        v = ep[gid * 6 + (c - 10)];
    }
    feat[idx] = v;
}

// ---------------- generic fp32 GEMM: C = epi(A[M,K]@B[K,*] + bias [+resid, LN]) --------
// block 256 thr = 4 waves; 64 rows/block (16 rows/wave), 192 cols/block (3 cols/lane)
// grid.x = M/64, grid.y = ncols/192. EPI: 0 none, 1 relu, 2 residual+bias+LN (ncols==192)
template <int EPI>
__global__ __launch_bounds__(256)
void gemm_kernel(const float* __restrict__ A, const float* __restrict__ B,
                 const float* __restrict__ bias, const float* __restrict__ resid,
                 const float* __restrict__ lng, const float* __restrict__ lnb,
                 float* __restrict__ C, int K, int ldb, int ldc) {
    __shared__ float sA[64 * 68];
    const int tid = threadIdx.x;
    const int wave = tid >> 6;
    const int lane = tid & 63;
    const int rbase = blockIdx.x * 64;
    const int cbase = blockIdx.y * 192;
    const int c0 = cbase + lane;

    float acc[16][3];
#pragma unroll
    for (int r = 0; r < 16; ++r) { acc[r][0] = 0.f; acc[r][1] = 0.f; acc[r][2] = 0.f; }

    for (int kc = 0; kc < K; kc += 64) {
        const int CH = min(64, K - kc);
        __syncthreads();
        for (int i = tid; i < 64 * CH; i += 256) {
            int r = i / CH, kk = i - r * CH;
            sA[r * 68 + kk] = A[(size_t)(rbase + r) * K + kc + kk];
        }
        __syncthreads();
        const float* Bp = B + (size_t)kc * ldb + c0;
        for (int k4 = 0; k4 < CH; k4 += 4) {
            const float* bp = Bp + (size_t)k4 * ldb;
            float b00 = bp[0],       b01 = bp[64],            b02 = bp[128];
            float b10 = bp[ldb],     b11 = bp[ldb + 64],      b12 = bp[ldb + 128];
            float b20 = bp[2 * ldb], b21 = bp[2 * ldb + 64],  b22 = bp[2 * ldb + 128];
            float b30 = bp[3 * ldb], b31 = bp[3 * ldb + 64],  b32 = bp[3 * ldb + 128];
#pragma unroll
            for (int r = 0; r < 16; ++r) {
                float4 a = *reinterpret_cast<const float4*>(&sA[(wave * 16 + r) * 68 + k4]);
                acc[r][0] = fmaf(a.x, b00, fmaf(a.y, b10, fmaf(a.z, b20, fmaf(a.w, b30, acc[r][0]))));
                acc[r][1] = fmaf(a.x, b01, fmaf(a.y, b11, fmaf(a.z, b21, fmaf(a.w, b31, acc[r][1]))));
                acc[r][2] = fmaf(a.x, b02, fmaf(a.y, b12, fmaf(a.z, b22, fmaf(a.w, b32, acc[r][2]))));
            }
        }
    }

    const int row0 = rbase + wave * 16;
    float bb0 = 0.f, bb1 = 0.f, bb2 = 0.f;
    if (bias) { bb0 = bias[c0]; bb1 = bias[c0 + 64]; bb2 = bias[c0 + 128]; }

    if (EPI == 2) {
        float g0 = lng[c0], g1 = lng[c0 + 64], g2 = lng[c0 + 128];
        float e0 = lnb[c0], e1 = lnb[c0 + 64], e2 = lnb[c0 + 128];
#pragma unroll
        for (int r = 0; r < 16; ++r) {
            size_t ro = (size_t)(row0 + r) * 192;
            float v0 = acc[r][0] + bb0 + resid[ro + c0];
            float v1 = acc[r][1] + bb1 + resid[ro + c0 + 64];
            float v2 = acc[r][2] + bb2 + resid[ro + c0 + 128];
            float s = v0 + v1 + v2;
            float q = v0 * v0 + v1 * v1 + v2 * v2;
#pragma unroll
            for (int off = 32; off > 0; off >>= 1) {
                s += __shfl_xor(s, off);
                q += __shfl_xor(q, off);
            }
            float mean = s * (1.f / 192.f);
            float var = q * (1.f / 192.f) - mean * mean;
            float rs = rsqrtf(var + 1e-5f);
            C[ro + c0]       = (v0 - mean) * rs * g0 + e0;
            C[ro + c0 + 64]  = (v1 - mean) * rs * g1 + e1;
            C[ro + c0 + 128] = (v2 - mean) * rs * g2 + e2;
        }
    } else {
#pragma unroll
        for (int r = 0; r < 16; ++r) {
            size_t ro = (size_t)(row0 + r) * ldc + c0;
            float v0 = acc[r][0] + bb0;
            float v1 = acc[r][1] + bb1;
            float v2 = acc[r][2] + bb2;
            if (EPI == 1) { v0 = fmaxf(v0, 0.f); v1 = fmaxf(v1, 0.f); v2 = fmaxf(v2, 0.f); }
            C[ro] = v0; C[ro + 64] = v1; C[ro + 128] = v2;
        }
    }
}

// ---------------- edge attention, one wave per destination node (online softmax) -------
__global__ __launch_bounds__(64)
void attn_kernel(const float* __restrict__ q, const float* __restrict__ k,
                 const float* __restrict__ v, const float* __restrict__ ea,
                 const float* __restrict__ We_l, const int* __restrict__ src,
                 const int* __restrict__ row_ptr, const int* __restrict__ csr_eid,
                 float* __restrict__ msg) {
    __shared__ float sWe[4 * 192];
    const int lane = threadIdx.x;
    for (int i = lane; i < 768; i += 64) sWe[i] = We_l[i];
    __syncthreads();

    const int node = blockIdx.x;
    const int h = lane >> 4, t = lane & 15;
    const int d0 = h * 48 + t * 3;
    const float scale = 0.14433756729740643f;  // 1/sqrt(48)
    size_t qb = (size_t)node * 192 + d0;
    float q0 = q[qb] * scale, q1 = q[qb + 1] * scale, q2 = q[qb + 2] * scale;

    float m = -INFINITY, den = 0.f, a0 = 0.f, a1 = 0.f, a2 = 0.f;
    const int beg = row_ptr[node], end = row_ptr[node + 1];
    for (int p = beg; p < end; ++p) {
        int e = csr_eid[p];
        int s = src[e];
        float w0 = ea[e * 4], w1 = ea[e * 4 + 1], w2 = ea[e * 4 + 2], w3 = ea[e * 4 + 3];
        float e0 = w0 * sWe[d0]     + w1 * sWe[192 + d0]     + w2 * sWe[384 + d0]     + w3 * sWe[576 + d0];
        float e1 = w0 * sWe[d0 + 1] + w1 * sWe[192 + d0 + 1] + w2 * sWe[384 + d0 + 1] + w3 * sWe[576 + d0 + 1];
        float e2 = w0 * sWe[d0 + 2] + w1 * sWe[192 + d0 + 2] + w2 * sWe[384 + d0 + 2] + w3 * sWe[576 + d0 + 2];
        size_t sb = (size_t)s * 192 + d0;
        float ke0 = k[sb] + e0, ke1 = k[sb + 1] + e1, ke2 = k[sb + 2] + e2;
        float part = q0 * ke0 + q1 * ke1 + q2 * ke2;
        part += __shfl_xor(part, 1);
        part += __shfl_xor(part, 2);
        part += __shfl_xor(part, 4);
        part += __shfl_xor(part, 8);
        float logit = part;
        float mn = fmaxf(m, logit);
        float corr = __expf(m - mn);       // first edge: exp(-inf) = 0
        float pe = __expf(logit - mn);
        float ve0 = v[sb] + e0, ve1 = v[sb + 1] + e1, ve2 = v[sb + 2] + e2;
        den = den * corr + pe;
        a0 = a0 * corr + pe * ve0;
        a1 = a1 * corr + pe * ve1;
        a2 = a2 * corr + pe * ve2;
        m = mn;
    }
    float inv = 1.f / (den + 1e-16f);
    size_t ob = (size_t)node * 192 + d0;
    msg[ob] = a0 * inv; msg[ob + 1] = a1 * inv; msg[ob + 2] = a2 * inv;
}

// ---------------- fused edge head: relu(Hs[src]+Hd[dst]+ea@W1e+b1) @ W2 -> relu -> W3 --
#define ETILE 32
__global__ __launch_bounds__(256)
void edge_head_kernel(const float* __restrict__ Hs, const float* __restrict__ Hd,
                      const float* __restrict__ ea, const int* __restrict__ src,
                      const int* __restrict__ dst, const float* __restrict__ W1e,
                      const float* __restrict__ b1, const float* __restrict__ W2,
                      const float* __restrict__ b2, const float* __restrict__ W3,
                      const float* __restrict__ b3, float* __restrict__ out) {
    __shared__ float sz1[ETILE * 196];
    __shared__ unsigned short sW2[192 * 96];
    const int tid = threadIdx.x;
    const int ebase = blockIdx.x * ETILE;

    for (int i = tid; i < 192 * 96; i += 256) sW2[i] = f2bf(W2[i]);
    for (int i = tid; i < ETILE * 192; i += 256) {
        int el = i / 192, c = i - el * 192;
        int e = ebase + el;
        int s = src[e], d = dst[e];
        float t = Hs[(size_t)s * 192 + c] + Hd[(size_t)d * 192 + c] + b1[c];
        float w0 = ea[e * 4], w1 = ea[e * 4 + 1], w2 = ea[e * 4 + 2], w3 = ea[e * 4 + 3];
        t += w0 * W1e[c] + w1 * W1e[192 + c] + w2 * W1e[384 + c] + w3 * W1e[576 + c];
        sz1[el * 196 + c] = fmaxf(t, 0.f);
    }
    __syncthreads();

    const int wave = tid >> 6, lane = tid & 63;
    const int r0 = wave * 8;
    const bool has2 = lane < 32;
    const int c0 = lane, c1 = lane + 64;
    float acc[8][2];
#pragma unroll
    for (int r = 0; r < 8; ++r) { acc[r][0] = 0.f; acc[r][1] = 0.f; }

    for (int k4 = 0; k4 < 192; k4 += 4) {
        float w0v[4], w1v[4];
#pragma unroll
        for (int kk = 0; kk < 4; ++kk) {
            w0v[kk] = bf2f(sW2[(k4 + kk) * 96 + c0]);
            w1v[kk] = has2 ? bf2f(sW2[(k4 + kk) * 96 + c1]) : 0.f;
        }
#pragma unroll
        for (int r = 0; r < 8; ++r) {
            float4 a = *reinterpret_cast<const float4*>(&sz1[(r0 + r) * 196 + k4]);
            acc[r][0] = fmaf(a.x, w0v[0], fmaf(a.y, w0v[1], fmaf(a.z, w0v[2], fmaf(a.w, w0v[3], acc[r][0]))));
            acc[r][1] = fmaf(a.x, w1v[0], fmaf(a.y, w1v[1], fmaf(a.z, w1v[2], fmaf(a.w, w1v[3], acc[r][1]))));
        }
    }

    float w3a = W3[c0];
    float w3b = has2 ? W3[c1] : 0.f;
    float bb0 = b2[c0];
    float bb1 = has2 ? b2[c1] : 0.f;
    float outp[8];
#pragma unroll
    for (int r = 0; r < 8; ++r) {
        float z0 = fmaxf(acc[r][0] + bb0, 0.f);
        float z1 = fmaxf(acc[r][1] + bb1, 0.f);
        float s = z0 * w3a + z1 * w3b;
#pragma unroll
        for (int off = 32; off > 0; off >>= 1) s += __shfl_xor(s, off);
        outp[r] = s;
    }
    if (lane == 0) {
        float b3v = b3[0];
#pragma unroll
        for (int r = 0; r < 8; ++r) out[ebase + r0 + r] = outp[r] + b3v;
    }
}

extern "C" void kernel_launch(void* const* d_in, const int* in_sizes, int n_in,
                              void* d_out, int out_size, void* d_ws, size_t ws_size,
                              hipStream_t stream) {
    const float* x    = (const float*)d_in[0];
    const int*   eidx = (const int*)d_in[1];
    const float* ea   = (const float*)d_in[2];
    const int*   batch = (const int*)d_in[3];
    const int*   gptr  = (const int*)d_in[4];
    const int*   tgid  = (const int*)d_in[5];
    const float* gp   = (const float*)d_in[6];
    const float* sp   = (const float*)d_in[7];
    const float* epp  = (const float*)d_in[8];
    const float* W_in = (const float*)d_in[9];
    const float* b_in = (const float*)d_in[10];
    const float* Wq   = (const float*)d_in[11];
    const float* Wk   = (const float*)d_in[12];
    const float* Wv   = (const float*)d_in[13];
    const float* We   = (const float*)d_in[14];
    const float* Wo   = (const float*)d_in[15];
    const float* bo   = (const float*)d_in[16];
    const float* ln1g = (const float*)d_in[17];
    const float* ln1b = (const float*)d_in[18];
    const float* Wf1  = (const float*)d_in[19];
    const float* bf1  = (const float*)d_in[20];
    const float* Wf2  = (const float*)d_in[21];
    const float* bf2  = (const float*)d_in[22];
    const float* ln2g = (const float*)d_in[23];
    const float* ln2b = (const float*)d_in[24];
    const float* We1  = (const float*)d_in[25];
    const float* be1  = (const float*)d_in[26];
    const float* We2  = (const float*)d_in[27];
    const float* be2  = (const float*)d_in[28];
    const float* We3  = (const float*)d_in[29];
    const float* be3  = (const float*)d_in[30];
    const int* src = eidx;
    const int* dst = eidx + N_EDGES;

    float* fw   = (float*)d_ws;
    float* feat = fw;                       // N*16
    float* qb   = feat + (size_t)N_NODES * 16;
    float* kb   = qb + (size_t)N_NODES * 192;
    float* vb   = kb + (size_t)N_NODES * 192;
    float* msg  = vb + (size_t)N_NODES * 192;
    float* hcur = msg + (size_t)N_NODES * 192;
    float* htmp = hcur + (size_t)N_NODES * 192;
    float* ff1  = qb;                        // alias q+k region (N*384) during FFN
    int* cnt  = (int*)(htmp + (size_t)N_NODES * 192);
    int* rowp = cnt + N_NODES;
    int* curs = rowp + N_NODES + 1;
    int* csr  = curs + N_NODES;

    hipMemsetAsync(cnt, 0, N_NODES * sizeof(int), stream);
    count_kernel<<<(N_EDGES + 255) / 256, 256, 0, stream>>>(dst, cnt, N_EDGES);
    scan_kernel<<<1, 1024, 0, stream>>>(cnt, rowp, curs, N_NODES);
    scatter_kernel<<<(N_EDGES + 255) / 256, 256, 0, stream>>>(dst, curs, csr, N_EDGES);
    feat_kernel<<<(N_NODES * 16 + 255) / 256, 256, 0, stream>>>(x, batch, gptr, tgid, gp, sp, epp, feat, N_NODES);

    dim3 g1(625, 1), g2(625, 2), blk(256);
    gemm_kernel<0><<<g1, blk, 0, stream>>>(feat, W_in, b_in, nullptr, nullptr, nullptr, hcur, 16, 192, 192);

    for (int l = 0; l < 3; ++l) {
        const float* Wq_l = Wq + (size_t)l * 192 * 192;
        const float* Wk_l = Wk + (size_t)l * 192 * 192;
        const float* Wv_l = Wv + (size_t)l * 192 * 192;
        const float* We_l = We + (size_t)l * 4 * 192;
        const float* Wo_l = Wo + (size_t)l * 192 * 192;
        gemm_kernel<0><<<g1, blk, 0, stream>>>(hcur, Wq_l, nullptr, nullptr, nullptr, nullptr, qb, 192, 192, 192);
        gemm_kernel<0><<<g1, blk, 0, stream>>>(hcur, Wk_l, nullptr, nullptr, nullptr, nullptr, kb, 192, 192, 192);
        gemm_kernel<0><<<g1, blk, 0, stream>>>(hcur, Wv_l, nullptr, nullptr, nullptr, nullptr, vb, 192, 192, 192);
        attn_kernel<<<N_NODES, 64, 0, stream>>>(qb, kb, vb, ea, We_l, src, rowp, csr, msg);
        gemm_kernel<2><<<g1, blk, 0, stream>>>(msg, Wo_l, bo + l * 192, hcur, ln1g + l * 192, ln1b + l * 192,
                                               htmp, 192, 192, 192);
        gemm_kernel<1><<<g2, blk, 0, stream>>>(htmp, Wf1 + (size_t)l * 192 * 384, bf1 + l * 384,
                                               nullptr, nullptr, nullptr, ff1, 192, 384, 384);
        gemm_kernel<2><<<g1, blk, 0, stream>>>(ff1, Wf2 + (size_t)l * 384 * 192, bf2 + l * 192, htmp,
                                               ln2g + l * 192, ln2b + l * 192, hcur, 384, 192, 192);
    }

    // edge head pre-projections: Hs = h@W_e1[0:192], Hd = h@W_e1[192:384]
    gemm_kernel<0><<<g1, blk, 0, stream>>>(hcur, We1, nullptr, nullptr, nullptr, nullptr, qb, 192, 192, 192);
    gemm_kernel<0><<<g1, blk, 0, stream>>>(hcur, We1 + 192 * 192, nullptr, nullptr, nullptr, nullptr, kb, 192, 192, 192);
    edge_head_kernel<<<N_EDGES / ETILE, blk, 0, stream>>>(qb, kb, ea, src, dst, We1 + 384 * 192,
                                                          be1, We2, be2, We3, be3, (float*)d_out);
}

// Round 2
// 1075.149 us; speedup vs baseline: 2.9189x; 2.9189x over previous
//
#include <hip/hip_runtime.h>
#include <hip/hip_bf16.h>
#include <math.h>

#define N_NODES 40000
#define N_EDGES 400000
#define GCLIP 511

using short8  = __attribute__((ext_vector_type(8))) short;
using ushort8 = __attribute__((ext_vector_type(8))) unsigned short;
using floatx4 = __attribute__((ext_vector_type(4))) float;

__device__ __forceinline__ void split_bf16(float v, unsigned short& hi, unsigned short& lo) {
    __hip_bfloat16 h = __float2bfloat16(v);
    float r = v - __bfloat162float(h);
    __hip_bfloat16 l = __float2bfloat16(r);
    hi = *(unsigned short*)&h;
    lo = *(unsigned short*)&l;
}

__device__ __forceinline__ floatx4 mfma16(short8 a, short8 b, floatx4 c) {
    return __builtin_amdgcn_mfma_f32_16x16x32_bf16(a, b, c, 0, 0, 0);
}

// ---------------- CSR build ----------------
__global__ void count_kernel(const int* __restrict__ dst, int* __restrict__ cnt, int E) {
    int e = blockIdx.x * 256 + threadIdx.x;
    if (e < E) atomicAdd(&cnt[dst[e]], 1);
}

__global__ void scan_kernel(const int* __restrict__ cnt, int* __restrict__ row_ptr,
                            int* __restrict__ cursor, int n) {
    __shared__ int wsum[16];
    __shared__ int woff[16];
    int tid = threadIdx.x, wave = tid >> 6, lane = tid & 63;
    int running = 0;
    for (int base = 0; base < n; base += 1024) {
        int i = base + tid;
        int v = (i < n) ? cnt[i] : 0;
        int x = v;
        for (int off = 1; off < 64; off <<= 1) {
            int t = __shfl_up(x, off);
            if (lane >= off) x += t;
        }
        if (lane == 63) wsum[wave] = x;
        __syncthreads();
        if (wave == 0 && lane < 16) {
            int s = wsum[lane];
            for (int off = 1; off < 16; off <<= 1) {
                int t = __shfl_up(s, off);
                if (lane >= off) s += t;
            }
            woff[lane] = s;
        }
        __syncthreads();
        int waveoff = (wave == 0) ? 0 : woff[wave - 1];
        int incl = x + waveoff;
        if (i < n) { int ex = running + incl - v; row_ptr[i] = ex; cursor[i] = ex; }
        running += woff[15];
        __syncthreads();
    }
    if (tid == 0) row_ptr[n] = running;
}

__global__ void scatter_kernel(const int* __restrict__ dst, int* __restrict__ cursor,
                               int* __restrict__ csr_eid, int E) {
    int e = blockIdx.x * 256 + threadIdx.x;
    if (e < E) {
        int pos = atomicAdd(&cursor[dst[e]], 1);
        csr_eid[pos] = e;
    }
}

// ---------------- feature build ----------------
__global__ void feat_kernel(const float* __restrict__ x, const int* __restrict__ batch,
                            const int* __restrict__ gptr, const int* __restrict__ tgid,
                            const float* __restrict__ gp, const float* __restrict__ sp,
                            const float* __restrict__ ep, float* __restrict__ feat, int n) {
    int idx = blockIdx.x * 256 + threadIdx.x;
    if (idx >= n * 16) return;
    int node = idx >> 4, c = idx & 15;
    float v;
    if (c < 4) {
        v = x[node * 4 + c];
    } else if (c < 7) {
        int gid = gptr[batch[node]] + tgid[node];
        gid = min(max(gid, 0), GCLIP);
        v = gp[gid * 3 + (c - 4)];
    } else if (c < 10) {
        v = sp[node * 3 + (c - 7)];
    } else {
        int gid = gptr[batch[node]] + tgid[node];
        gid = min(max(gid, 0), GCLIP);
        v = ep[gid * 6 + (c - 10)];
    }
    feat[idx] = v;
}

// ---------------- weight prep: transpose + hi/lo bf16 split into ws ----------------
// dest layout per matrix: [Nrows][Kpad] bf16, hi plane at wb[idx], lo at wb[WTOT+idx]
#define WOFF_WIN 0
#define WOFF_QKV 6144
#define WOFF_WO  337920
#define WOFF_WF1 448512
#define WOFF_WF2 669696
#define WOFF_HSD 890880
#define WOFF_WE2 964608
#define WTOT     983040

__global__ void prep_kernel(const float* __restrict__ W_in, const float* __restrict__ Wq,
                            const float* __restrict__ Wk, const float* __restrict__ Wv,
                            const float* __restrict__ Wo, const float* __restrict__ Wf1,
                            const float* __restrict__ Wf2, const float* __restrict__ We1,
                            const float* __restrict__ We2, unsigned short* __restrict__ wb) {
    int idx = blockIdx.x * 256 + threadIdx.x;
    if (idx >= WTOT) return;
    float val;
    if (idx < WOFF_QKV) {                       // W_in^T [192][32], K=16 padded
        int n = idx / 32, k = idx % 32;
        val = (k < 16) ? W_in[k * 192 + n] : 0.f;
    } else if (idx < WOFF_WO) {                 // Wqkv^T [576][192] x3
        int r = idx - WOFF_QKV; int l = r / 110592; r %= 110592;
        int n = r / 192, k = r % 192;
        const float* s = (n < 192) ? Wq : (n < 384 ? Wk : Wv);
        val = s[l * 36864 + k * 192 + (n % 192)];
    } else if (idx < WOFF_WF1) {                // Wo^T [192][192] x3
        int r = idx - WOFF_WO; int l = r / 36864; r %= 36864;
        int n = r / 192, k = r % 192;
        val = Wo[l * 36864 + k * 192 + n];
    } else if (idx < WOFF_WF2) {                // Wf1^T [384][192] x3
        int r = idx - WOFF_WF1; int l = r / 73728; r %= 73728;
        int n = r / 192, k = r % 192;
        val = Wf1[l * 73728 + k * 384 + n];
    } else if (idx < WOFF_HSD) {                // Wf2^T [192][384] x3
        int r = idx - WOFF_WF2; int l = r / 73728; r %= 73728;
        int n = r / 384, k = r % 384;
        val = Wf2[l * 73728 + k * 192 + n];
    } else if (idx < WOFF_WE2) {                // [Hs|Hd]^T [384][192]
        int r = idx - WOFF_HSD;
        int n = r / 192, k = r % 192;
        val = (n < 192) ? We1[k * 192 + n] : We1[(192 + k) * 192 + (n - 192)];
    } else {                                    // We2^T [96][192]
        int r = idx - WOFF_WE2;
        int n = r / 192, k = r % 192;
        val = We2[k * 96 + n];
    }
    unsigned short hi, lo;
    split_bf16(val, hi, lo);
    wb[idx] = hi;
    wb[WTOT + idx] = lo;
}

// ---------------- MFMA GEMM: C[M,N] = epi(A[M,K] @ B + bias [+resid, LN]) ------------
// hi/lo bf16 split on both operands -> fp32-level accuracy. BM=128, BN=192, BK=32.
// 4 waves; wave handles 32 rows x 192 cols = 2x12 tiles of 16x16, 3 MFMAs per tile-k.
// EPI: 0 plain(+bias), 1 relu(+bias), 2 bias+resid+LN (requires N=192, grid.y=1)
template <int EPI>
__global__ __launch_bounds__(256, 2)
void mfma_gemm(const float* __restrict__ A, int M, int K, int Kpad,
               const unsigned short* __restrict__ Bhi, const unsigned short* __restrict__ Blo,
               const float* __restrict__ bias, const float* __restrict__ resid,
               const float* __restrict__ lng, const float* __restrict__ lnb,
               float* __restrict__ C, int ldc) {
    __shared__ __align__(16) unsigned short sA[2][128][40];   // +8 pad: 2-way banks (free)
    __shared__ __align__(16) unsigned short sB[2][192][40];
    const int tid = threadIdx.x;
    const int wave = tid >> 6, lane = tid & 63;
    const int quad = lane >> 4, l16 = lane & 15;
    const int rbase = blockIdx.x * 128;
    const int cbase = blockIdx.y * 192;

    floatx4 acc[2][12];
#pragma unroll
    for (int mt = 0; mt < 2; ++mt)
#pragma unroll
        for (int nt = 0; nt < 12; ++nt) acc[mt][nt] = (floatx4)0.0f;

    const int arow = tid >> 1, ahalf = tid & 1;
    const int agr = min(rbase + arow, M - 1);
    const float* aptr = A + (size_t)agr * K + ahalf * 16;

    for (int kc = 0; kc < Kpad; kc += 32) {
        // ---- stage A (fp32 -> hi/lo bf16), 16 values per thread ----
        float f[16];
        if (kc + ahalf * 16 < K) {
            const float4* p = (const float4*)(aptr + kc);
#pragma unroll
            for (int j = 0; j < 4; ++j) {
                float4 xv = p[j];
                f[j * 4 + 0] = xv.x; f[j * 4 + 1] = xv.y;
                f[j * 4 + 2] = xv.z; f[j * 4 + 3] = xv.w;
            }
        } else {
#pragma unroll
            for (int j = 0; j < 16; ++j) f[j] = 0.f;
        }
        ushort8 hv0, hv1, lv0, lv1;
#pragma unroll
        for (int j = 0; j < 8; ++j) {
            unsigned short hi, lo;
            split_bf16(f[j], hi, lo);     hv0[j] = hi; lv0[j] = lo;
            split_bf16(f[8 + j], hi, lo); hv1[j] = hi; lv1[j] = lo;
        }
        *(ushort8*)&sA[0][arow][ahalf * 16]     = hv0;
        *(ushort8*)&sA[0][arow][ahalf * 16 + 8] = hv1;
        *(ushort8*)&sA[1][arow][ahalf * 16]     = lv0;
        *(ushort8*)&sA[1][arow][ahalf * 16 + 8] = lv1;
        // ---- stage B (pre-split bf16 planes, straight copy) ----
#pragma unroll
        for (int it = 0; it < 6; ++it) {
            int i = it * 256 + tid;                    // 1536 = 2 planes * 192 rows * 4 quads
            int plane = i / 768, r2 = i % 768;
            int n = r2 >> 2, qq = r2 & 3;
            const unsigned short* sp = (plane ? Blo : Bhi) + (size_t)(cbase + n) * Kpad + kc + qq * 8;
            *(uint4*)&sB[plane][n][qq * 8] = *(const uint4*)sp;
        }
        __syncthreads();
        // ---- compute ----
        short8 ah0 = *(const short8*)&sA[0][wave * 32 + l16][quad * 8];
        short8 ah1 = *(const short8*)&sA[0][wave * 32 + 16 + l16][quad * 8];
        short8 al0 = *(const short8*)&sA[1][wave * 32 + l16][quad * 8];
        short8 al1 = *(const short8*)&sA[1][wave * 32 + 16 + l16][quad * 8];
#pragma unroll
        for (int nt = 0; nt < 12; ++nt) {
            short8 bh = *(const short8*)&sB[0][nt * 16 + l16][quad * 8];
            short8 bl = *(const short8*)&sB[1][nt * 16 + l16][quad * 8];
            acc[0][nt] = mfma16(ah0, bh, acc[0][nt]);
            acc[0][nt] = mfma16(al0, bh, acc[0][nt]);
            acc[0][nt] = mfma16(ah0, bl, acc[0][nt]);
            acc[1][nt] = mfma16(ah1, bh, acc[1][nt]);
            acc[1][nt] = mfma16(al1, bh, acc[1][nt]);
            acc[1][nt] = mfma16(ah1, bl, acc[1][nt]);
        }
        __syncthreads();
    }

    // ---- epilogue ----
    float bb[12], gg[12], be[12];
#pragma unroll
    for (int nt = 0; nt < 12; ++nt) {
        int col = cbase + nt * 16 + l16;
        bb[nt] = bias ? bias[col] : 0.f;
        if (EPI == 2) { gg[nt] = lng[col]; be[nt] = lnb[col]; }
    }
#pragma unroll
    for (int mt = 0; mt < 2; ++mt) {
#pragma unroll
        for (int reg = 0; reg < 4; ++reg) {
            int row = rbase + wave * 32 + mt * 16 + quad * 4 + reg;
            if (EPI == 2) {
                int rr = min(row, M - 1);
                float v[12], s = 0.f, q = 0.f;
#pragma unroll
                for (int nt = 0; nt < 12; ++nt) {
                    v[nt] = acc[mt][nt][reg] + bb[nt] + resid[(size_t)rr * 192 + nt * 16 + l16];
                    s += v[nt]; q += v[nt] * v[nt];
                }
#pragma unroll
                for (int off = 1; off < 16; off <<= 1) {
                    s += __shfl_xor(s, off);
                    q += __shfl_xor(q, off);
                }
                float mean = s * (1.f / 192.f);
                float var = q * (1.f / 192.f) - mean * mean;
                float rs = rsqrtf(var + 1e-5f);
                if (row < M) {
#pragma unroll
                    for (int nt = 0; nt < 12; ++nt)
                        C[(size_t)row * 192 + nt * 16 + l16] = (v[nt] - mean) * rs * gg[nt] + be[nt];
                }
            } else {
                if (row < M) {
#pragma unroll
                    for (int nt = 0; nt < 12; ++nt) {
                        float v = acc[mt][nt][reg] + bb[nt];
                        if (EPI == 1) v = fmaxf(v, 0.f);
                        C[(size_t)row * ldc + cbase + nt * 16 + l16] = v;
                    }
                }
            }
        }
    }
}

// ---------------- edge attention (fp32, online softmax), qkv packed stride 576 --------
__global__ __launch_bounds__(64)
void attn_kernel(const float* __restrict__ qkv, const float* __restrict__ ea,
                 const float* __restrict__ We_l, const int* __restrict__ src,
                 const int* __restrict__ row_ptr, const int* __restrict__ csr_eid,
                 float* __restrict__ msg) {
    __shared__ float sWe[4 * 192];
    const int lane = threadIdx.x;
    for (int i = lane; i < 768; i += 64) sWe[i] = We_l[i];
    __syncthreads();

    const int node = blockIdx.x;
    const int d0 = (lane >> 4) * 48 + (lane & 15) * 3;
    const float scale = 0.14433756729740643f;  // 1/sqrt(48)
    size_t qb = (size_t)node * 576 + d0;
    float q0 = qkv[qb] * scale, q1 = qkv[qb + 1] * scale, q2 = qkv[qb + 2] * scale;

    float m = -INFINITY, den = 0.f, a0 = 0.f, a1 = 0.f, a2 = 0.f;
    const int beg = row_ptr[node], end = row_ptr[node + 1];
    for (int p = beg; p < end; ++p) {
        int e = csr_eid[p];
        int s = src[e];
        float w0 = ea[e * 4], w1 = ea[e * 4 + 1], w2 = ea[e * 4 + 2], w3 = ea[e * 4 + 3];
        float e0 = w0 * sWe[d0]     + w1 * sWe[192 + d0]     + w2 * sWe[384 + d0]     + w3 * sWe[576 + d0];
        float e1 = w0 * sWe[d0 + 1] + w1 * sWe[192 + d0 + 1] + w2 * sWe[384 + d0 + 1] + w3 * sWe[576 + d0 + 1];
        float e2 = w0 * sWe[d0 + 2] + w1 * sWe[192 + d0 + 2] + w2 * sWe[384 + d0 + 2] + w3 * sWe[576 + d0 + 2];
        size_t sb = (size_t)s * 576 + 192 + d0;       // k at +192, v at +384
        float ke0 = qkv[sb] + e0, ke1 = qkv[sb + 1] + e1, ke2 = qkv[sb + 2] + e2;
        float part = q0 * ke0 + q1 * ke1 + q2 * ke2;
        part += __shfl_xor(part, 1);
        part += __shfl_xor(part, 2);
        part += __shfl_xor(part, 4);
        part += __shfl_xor(part, 8);
        float logit = part;
        float mn = fmaxf(m, logit);
        float corr = __expf(m - mn);
        float pe = __expf(logit - mn);
        float ve0 = qkv[sb + 192] + e0, ve1 = qkv[sb + 193] + e1, ve2 = qkv[sb + 194] + e2;
        den = den * corr + pe;
        a0 = a0 * corr + pe * ve0;
        a1 = a1 * corr + pe * ve1;
        a2 = a2 * corr + pe * ve2;
        m = mn;
    }
    float inv = 1.f / (den + 1e-16f);
    size_t ob = (size_t)node * 192 + d0;
    msg[ob] = a0 * inv; msg[ob + 1] = a1 * inv; msg[ob + 2] = a2 * inv;
}

// ---------------- edge head: gather z1 -> MFMA (192->96) -> relu -> W3 ----------------
// 64 edges/block, K chunked by 32. hsd packed [N,384]: Hs cols 0..191, Hd cols 192..383.
__global__ __launch_bounds__(256, 2)
void edge_head_kernel(const float* __restrict__ hsd, const float* __restrict__ ea,
                      const int* __restrict__ src, const int* __restrict__ dst,
                      const float* __restrict__ W1e, const float* __restrict__ b1,
                      const unsigned short* __restrict__ W2hi, const unsigned short* __restrict__ W2lo,
                      const float* __restrict__ b2, const float* __restrict__ W3,
                      const float* __restrict__ b3, float* __restrict__ out) {
    __shared__ __align__(16) unsigned short sZ[2][64][40];
    __shared__ __align__(16) unsigned short sW[2][96][40];
    __shared__ float sWe1[768];
    __shared__ float sB1[192];
    const int tid = threadIdx.x;
    const int wave = tid >> 6, lane = tid & 63;
    const int quad = lane >> 4, l16 = lane & 15;
    const int ebase = blockIdx.x * 64;

    for (int i = tid; i < 768; i += 256) sWe1[i] = W1e[i];
    if (tid < 192) sB1[tid] = b1[tid];

    const int el = tid >> 2, part = tid & 3;
    const int e = ebase + el;
    const int s = src[e], d = dst[e];
    const float4 eav = *(const float4*)(ea + (size_t)e * 4);
    const float* hs_p = hsd + (size_t)s * 384;
    const float* hd_p = hsd + (size_t)d * 384 + 192;

    floatx4 acc[6];
#pragma unroll
    for (int nt = 0; nt < 6; ++nt) acc[nt] = (floatx4)0.0f;
    __syncthreads();

    for (int kc = 0; kc < 192; kc += 32) {
        // stage z1 = relu(Hs[s] + Hd[d] + ea@W1e + b1), hi/lo split
        {
            int c0 = kc + part * 8;
            float4 a0 = *(const float4*)(hs_p + c0);
            float4 a1 = *(const float4*)(hs_p + c0 + 4);
            float4 b0 = *(const float4*)(hd_p + c0);
            float4 b1v = *(const float4*)(hd_p + c0 + 4);
            float f[8] = {a0.x + b0.x, a0.y + b0.y, a0.z + b0.z, a0.w + b0.w,
                          a1.x + b1v.x, a1.y + b1v.y, a1.z + b1v.z, a1.w + b1v.w};
            ushort8 hv, lv;
#pragma unroll
            for (int j = 0; j < 8; ++j) {
                int c = c0 + j;
                float ce = sB1[c] + eav.x * sWe1[c] + eav.y * sWe1[192 + c]
                         + eav.z * sWe1[384 + c] + eav.w * sWe1[576 + c];
                float v = fmaxf(f[j] + ce, 0.f);
                unsigned short hi, lo;
                split_bf16(v, hi, lo);
                hv[j] = hi; lv[j] = lo;
            }
            *(ushort8*)&sZ[0][el][part * 8] = hv;
            *(ushort8*)&sZ[1][el][part * 8] = lv;
        }
        // stage W2 chunk: 768 = 2 planes * 96 rows * 4 quads
#pragma unroll
        for (int it = 0; it < 3; ++it) {
            int i = it * 256 + tid;
            int plane = i / 384, r2 = i % 384;
            int n = r2 >> 2, qq = r2 & 3;
            const unsigned short* sp = (plane ? W2lo : W2hi) + (size_t)n * 192 + kc + qq * 8;
            *(uint4*)&sW[plane][n][qq * 8] = *(const uint4*)sp;
        }
        __syncthreads();
        short8 ah = *(const short8*)&sZ[0][wave * 16 + l16][quad * 8];
        short8 al = *(const short8*)&sZ[1][wave * 16 + l16][quad * 8];
#pragma unroll
        for (int nt = 0; nt < 6; ++nt) {
            short8 bh = *(const short8*)&sW[0][nt * 16 + l16][quad * 8];
            short8 bl = *(const short8*)&sW[1][nt * 16 + l16][quad * 8];
            acc[nt] = mfma16(ah, bh, acc[nt]);
            acc[nt] = mfma16(al, bh, acc[nt]);
            acc[nt] = mfma16(ah, bl, acc[nt]);
        }
        __syncthreads();
    }

    float w3[6], bb2[6];
#pragma unroll
    for (int nt = 0; nt < 6; ++nt) {
        int col = nt * 16 + l16;
        w3[nt] = W3[col];
        bb2[nt] = b2[col];
    }
    float b3v = b3[0];
#pragma unroll
    for (int reg = 0; reg < 4; ++reg) {
        float sacc = 0.f;
#pragma unroll
        for (int nt = 0; nt < 6; ++nt) {
            float z = fmaxf(acc[nt][reg] + bb2[nt], 0.f);
            sacc = fmaf(z, w3[nt], sacc);
        }
#pragma unroll
        for (int off = 1; off < 16; off <<= 1) sacc += __shfl_xor(sacc, off);
        if (l16 == 0) out[ebase + wave * 16 + quad * 4 + reg] = sacc + b3v;
    }
}

extern "C" void kernel_launch(void* const* d_in, const int* in_sizes, int n_in,
                              void* d_out, int out_size, void* d_ws, size_t ws_size,
                              hipStream_t stream) {
    const float* x     = (const float*)d_in[0];
    const int*   eidx  = (const int*)d_in[1];
    const float* ea    = (const float*)d_in[2];
    const int*   batch = (const int*)d_in[3];
    const int*   gptr  = (const int*)d_in[4];
    const int*   tgid  = (const int*)d_in[5];
    const float* gp    = (const float*)d_in[6];
    const float* sp    = (const float*)d_in[7];
    const float* epp   = (const float*)d_in[8];
    const float* W_in  = (const float*)d_in[9];
    const float* b_in  = (const float*)d_in[10];
    const float* Wq    = (const float*)d_in[11];
    const float* Wk    = (const float*)d_in[12];
    const float* Wv    = (const float*)d_in[13];
    const float* We    = (const float*)d_in[14];
    const float* Wo    = (const float*)d_in[15];
    const float* bo    = (const float*)d_in[16];
    const float* ln1g  = (const float*)d_in[17];
    const float* ln1b  = (const float*)d_in[18];
    const float* Wf1   = (const float*)d_in[19];
    const float* bf1   = (const float*)d_in[20];
    const float* Wf2   = (const float*)d_in[21];
    const float* bf2   = (const float*)d_in[22];
    const float* ln2g  = (const float*)d_in[23];
    const float* ln2b  = (const float*)d_in[24];
    const float* We1   = (const float*)d_in[25];
    const float* be1   = (const float*)d_in[26];
    const float* We2   = (const float*)d_in[27];
    const float* be2   = (const float*)d_in[28];
    const float* We3   = (const float*)d_in[29];
    const float* be3   = (const float*)d_in[30];
    const int* src = eidx;
    const int* dst = eidx + N_EDGES;

    float* fw   = (float*)d_ws;
    float* feat = fw;                               // 640000
    float* h    = feat + 640000;                    // 7.68M
    float* htmp = h + 7680000;                      // 7.68M
    float* msg  = htmp + 7680000;                   // 7.68M
    float* qkv  = msg + 7680000;                    // 23.04M (ff and hsd alias here)
    unsigned short* wb = (unsigned short*)(qkv + 23040000);  // 2*WTOT ushorts
    int* cnt  = (int*)(wb + 2 * WTOT);
    int* rowp = cnt + N_NODES;
    int* curs = rowp + N_NODES + 1;
    int* csr  = curs + N_NODES;

    hipMemsetAsync(cnt, 0, N_NODES * sizeof(int), stream);
    count_kernel<<<1563, 256, 0, stream>>>(dst, cnt, N_EDGES);
    scan_kernel<<<1, 1024, 0, stream>>>(cnt, rowp, curs, N_NODES);
    scatter_kernel<<<1563, 256, 0, stream>>>(dst, curs, csr, N_EDGES);
    feat_kernel<<<2500, 256, 0, stream>>>(x, batch, gptr, tgid, gp, sp, epp, feat, N_NODES);
    prep_kernel<<<3840, 256, 0, stream>>>(W_in, Wq, Wk, Wv, Wo, Wf1, Wf2, We1, We2, wb);

    const unsigned short* whi = wb;
    const unsigned short* wlo = wb + WTOT;
    dim3 blk(256);

    // input projection: feat[40000,16] @ W_in -> h
    mfma_gemm<0><<<dim3(313, 1), blk, 0, stream>>>(feat, N_NODES, 16, 32,
        whi + WOFF_WIN, wlo + WOFF_WIN, b_in, nullptr, nullptr, nullptr, h, 192);

    for (int l = 0; l < 3; ++l) {
        mfma_gemm<0><<<dim3(313, 3), blk, 0, stream>>>(h, N_NODES, 192, 192,
            whi + WOFF_QKV + l * 110592, wlo + WOFF_QKV + l * 110592,
            nullptr, nullptr, nullptr, nullptr, qkv, 576);
        attn_kernel<<<N_NODES, 64, 0, stream>>>(qkv, ea, We + l * 768, src, rowp, csr, msg);
        mfma_gemm<2><<<dim3(313, 1), blk, 0, stream>>>(msg, N_NODES, 192, 192,
            whi + WOFF_WO + l * 36864, wlo + WOFF_WO + l * 36864,
            bo + l * 192, h, ln1g + l * 192, ln1b + l * 192, htmp, 192);
        mfma_gemm<1><<<dim3(313, 2), blk, 0, stream>>>(htmp, N_NODES, 192, 192,
            whi + WOFF_WF1 + l * 73728, wlo + WOFF_WF1 + l * 73728,
            bf1 + l * 384, nullptr, nullptr, nullptr, qkv /*ff*/, 384);
        mfma_gemm<2><<<dim3(313, 1), blk, 0, stream>>>(qkv /*ff*/, N_NODES, 384, 384,
            whi + WOFF_WF2 + l * 73728, wlo + WOFF_WF2 + l * 73728,
            bf2 + l * 192, htmp, ln2g + l * 192, ln2b + l * 192, h, 192);
    }

    // edge head pre-projections: [Hs|Hd] = h @ [We1[0:192] | We1[192:384]]
    mfma_gemm<0><<<dim3(313, 2), blk, 0, stream>>>(h, N_NODES, 192, 192,
        whi + WOFF_HSD, wlo + WOFF_HSD, nullptr, nullptr, nullptr, nullptr, qkv /*hsd*/, 384);
    edge_head_kernel<<<6250, blk, 0, stream>>>(qkv /*hsd*/, ea, src, dst,
        We1 + 384 * 192, be1, whi + WOFF_WE2, wlo + WOFF_WE2, be2, We3, be3, (float*)d_out);
}